// Round 11
// baseline (227.244 us; speedup 1.0000x reference)
//
#include <hip/hip_runtime.h>
#include <hip/hip_fp16.h>
#include <math.h>

// Problem constants
#define NPIX   131072      // B*H*W = 32*64*64
#define KEMB   512
#define DDIM   64
#define HW     4096        // H*W
#define BSTRIDE 262144     // C*H*W

// d_out flat layout (float32): [loss(1) | out(8388608) | perplexity(1) | indices(131072)]
#define OUT_OFF  1
#define PERP_OFF 8388609
#define IDX_OFF  8388610

typedef __attribute__((ext_vector_type(8))) _Float16 f16x8;    // MFMA A/B frag (4 VGPRs)
typedef __attribute__((ext_vector_type(4))) float f32x4;       // MFMA C/D frag

// SESSION LEDGER (proven on this problem):
//  - R9 = 82us vq_main (total 153.5, prev best): f16 2-split K-loop, both
//    tables LDS (132KB), LDS prefetch pipeline, med3/min top-2, build-after-
//    barrier, 256x1024 @(1024,4), 16 waves/CU, fence-LESS ticket finalize.
//    Compiler landed at EXACTLY 64 VGPRs.
//  - R10 (setprio+gll+early-loads bundle) = 86us: setprio around near-lockstep
//    MFMA cluster is the suspect (catalog m190: negative on lockstep). Dropped.
//  - __threadfence() = ~2x curse (L2 WB/INV storm, R3/R4/R5). NEVER.
//  - FORCED reg caps <128 on a too-big live set spill (R1/R2). The live set
//    here is halved (16px/wave, el streamed) to make 64 fit honestly.
//  - In-K-loop global streams failed at LOW occupancy (R3, ~9 waves/CU avg);
//    R0 proved the same stream pattern works inside a fast kernel. This round
//    re-tests it at 32 waves/CU (2 blocks/CU) — that is the experiment.
//  - Occupancy QUANTIZED at vgpr {64,128}: <=64 regs -> 32 waves/CU possible.
//  - R11 (this): eh-only LDS (~70KB) + el streamed from L2 + 16px/wave +
//    (1024,8) 64-reg cap -> 2 blocks/CU, 32 waves. Distance/select/rescore
//    chains bitwise == R9 per candidate.
//
// 2-split f16 scheme (absmax 0 in R2..R10): x = h + l/2048 + r, |r|<=2^-21|x|.
// l pre-scaled by 2^11 (exact pow2) stays in f16 normal range. Products kept:
// hh + (h*l'+l'*h)/2048; dropped terms ~1e-4 absolute, and the exact fp32
// top-2 rescore decides the final index.

// ws layout: [0,2048) int counts | [2048,4096) float hnorms | [4096] loss |
//            [4160] done_ctr | [8192,73728) eh_t (f16 high, frag-linear, 64KB) |
//            [73728,139264) el_t (f16 low pre-scaled by 2^11, frag-linear, 64KB)
// frag-linear: idx = ct*1024 + ks*512 + (quad*16+col)*8 + j  (R5-proven).
__global__ void vq_init(const float* __restrict__ emb, int* __restrict__ counts,
                        float* __restrict__ hnorms, float* __restrict__ loss_acc,
                        int* __restrict__ done_ctr,
                        unsigned short* __restrict__ eh_t,
                        unsigned short* __restrict__ el_t) {
    const int k = blockIdx.x;             // code
    const int c = threadIdx.x;            // channel
    const int ct = k >> 4, cl = k & 15;
    const int ks = c >> 5, qd = (c >> 3) & 3, j = c & 7;
    float x = emb[k * DDIM + c];
    _Float16 h = (_Float16)x;             // v_cvt_f16_f32, RTNE
    float r1 = x - (float)h;              // exact (Sterbenz)
    _Float16 l = (_Float16)(r1 * 2048.0f);
    const int dst = ct * 1024 + ks * 512 + (qd * 16 + cl) * 8 + j;
    ((_Float16*)eh_t)[dst] = h;
    ((_Float16*)el_t)[dst] = l;
    float s = x * x;
#pragma unroll
    for (int off = 1; off <= 32; off <<= 1) s += __shfl_xor(s, off, 64);
    if (c == 0) {
        hnorms[k] = 0.5f * s;
        counts[k] = 0;
        if (k == 0) { *loss_acc = 0.f; *done_ctr = 0; }
    }
}

// 512 blocks x 1024 threads, 16 waves/block, 16 px/wave. LDS ~70KB (eh table
// only) + 64-reg cap -> 2 blocks/CU = 32 waves/CU. Al fragments stream from
// the L2-resident el table in-loop (coalesced 16B/lane); 8 waves/SIMD hide
// the latency. K-loop barrier-free.
__global__ __launch_bounds__(1024, 8) void vq_main(
    const float* __restrict__ in, const float* __restrict__ emb,
    const unsigned short* __restrict__ eh_t, const unsigned short* __restrict__ el_t,
    const float* __restrict__ hnorms, int* __restrict__ counts,
    float* __restrict__ loss_acc, int* __restrict__ done_ctr,
    float* __restrict__ dout)
{
    __shared__ __align__(16) _Float16 eh_l[KEMB * DDIM];   // 64 KB
    __shared__ __align__(16) float hn_lds[KEMB];           // 2 KB
    __shared__ int hist[KEMB];                             // 2 KB
    __shared__ float part[8];
    __shared__ int lastflag;

    const int t    = threadIdx.x;         // 0..1023
    const int lane = t & 63;
    const int wv   = t >> 6;              // wave id 0..15
    const int quad = lane >> 4;
    const int col  = lane & 15;
    const int b    = blockIdx.x >> 4;                        // 16 blocks per image
    const int p0   = ((blockIdx.x & 15) << 8) | (wv << 4);   // this wave's 16 px
    const float* xb = in + b * BSTRIDE;

    if (t < KEMB) hist[t] = 0;
    if (t < 128) ((float4*)hn_lds)[t] = ((const float4*)hnorms)[t];

    // ---- Stage h table into LDS: linear 16B/lane copies (proven pattern).
#pragma unroll
    for (int i = 0; i < 4; ++i) {
        const int f = (t + i * 1024) * 8;
        *(f16x8*)&eh_l[f] = *(const f16x8*)((const _Float16*)eh_t + f);
    }

    __syncthreads();   // table + hn + hist ready

    // ---- Build x B-fragments AFTER the barrier (R9-proven): registers only.
    f16x8 xh[2], xl[2];
#pragma unroll
    for (int s = 0; s < 2; ++s) {
        const int ppb = p0 + col;
        const int c0  = s * 32 + quad * 8;
        f16x8 vh, vl;
#pragma unroll
        for (int j = 0; j < 8; ++j) {
            float x = xb[(c0 + j) * HW + ppb];
            _Float16 h = (_Float16)x;
            float r1 = x - (float)h;
            vh[j] = h;
            vl[j] = (_Float16)(r1 * 2048.0f);
        }
        xh[s] = vh; xl[s] = vl;
    }

    // ---- K-loop over 32 code tiles: Ah from LDS, Al streamed from L2.
    // 6 MFMA/tile; acc0 accumulation order bitwise == R9's acc0.
    float v1 = 3.402823466e38f, v2 = 3.402823466e38f;
    int   k1 = 0, k2 = 0;
    const _Float16* elp = (const _Float16*)el_t;

    for (int ct = 0; ct < 32; ++ct) {
        const int base = ct * 1024 + lane * 8;
        const f16x8 Al0 = *(const f16x8*)(elp + base);        // global, L2-hot
        const f16x8 Al1 = *(const f16x8*)(elp + base + 512);
        const f16x8 Ah0 = *(const f16x8*)&eh_l[base];
        const f16x8 Ah1 = *(const f16x8*)&eh_l[base + 512];

        f32x4 ah = (f32x4){0.f, 0.f, 0.f, 0.f};
        f32x4 al = (f32x4){0.f, 0.f, 0.f, 0.f};
        ah = __builtin_amdgcn_mfma_f32_16x16x32_f16(Ah0, xh[0], ah, 0, 0, 0);
        al = __builtin_amdgcn_mfma_f32_16x16x32_f16(Ah0, xl[0], al, 0, 0, 0);
        al = __builtin_amdgcn_mfma_f32_16x16x32_f16(Al0, xh[0], al, 0, 0, 0);
        ah = __builtin_amdgcn_mfma_f32_16x16x32_f16(Ah1, xh[1], ah, 0, 0, 0);
        al = __builtin_amdgcn_mfma_f32_16x16x32_f16(Ah1, xl[1], al, 0, 0, 0);
        al = __builtin_amdgcn_mfma_f32_16x16x32_f16(Al1, xh[1], al, 0, 0, 0);

        const f32x4 hn = *(const f32x4*)&hn_lds[ct * 16 + quad * 4];
#pragma unroll
        for (int r = 0; r < 4; ++r) {
            const int kk = ct * 16 + quad * 4 + r;
            // med3/min top-2 update (R9-proven, selection-identical to strict-<)
            const float sc = hn[r] - (ah[r] + al[r] * 4.8828125e-4f);
            const bool c1 = sc < v1;
            const bool c2 = sc < v2;
            const int nk2 = c1 ? k1 : (c2 ? kk : k2);
            const int nk1 = c1 ? kk : k1;
            v2 = __builtin_amdgcn_fmed3f(v1, v2, sc);
            v1 = fminf(v1, sc);
            k1 = nk1; k2 = nk2;
        }
    }

    // Cross-quad top-2 merge: lanes l, l^16, l^32 share pixel-col (R0 verbatim,
    // single acc). After this, all 4 quad-lanes of a pixel hold merged top-2.
#pragma unroll
    for (int off = 16; off <= 32; off <<= 1) {
        float w1 = __shfl_xor(v1, off, 64); int j1 = __shfl_xor(k1, off, 64);
        float w2 = __shfl_xor(v2, off, 64); int j2 = __shfl_xor(k2, off, 64);
        bool aF = (v1 < w1) || (v1 == w1 && k1 < j1);
        float t1 = aF ? v1 : w1;  int u1 = aF ? k1 : j1;
        float tl = aF ? w1 : v1;  int ul = aF ? j1 : k1;      // loser of firsts
        bool bS = (v2 < w2) || (v2 == w2 && k2 < j2);
        float tc = bS ? v2 : w2;  int uc = bS ? k2 : j2;      // better of seconds
        bool lS = (tl < tc) || (tl == tc && ul < uc);
        v1 = t1; k1 = u1;
        v2 = lS ? tl : tc; k2 = lS ? ul : uc;
    }

    // Pixel q = lane&15. Quads {0,2} score kA, quads {1,3} score kB; partner
    // is lane^16. Rescore chain per candidate bitwise == the passing kernels.
    const int q    = lane & 15;
    const int pp   = p0 + q;
    const int kA   = k1, kB = k2;
    const int kMine = (lane & 16) ? kB : kA;
    const float4* eM = (const float4*)(emb + kMine * DDIM);
    float a0 = hn_lds[kMine], a1 = 0.f, a2 = 0.f, a3 = 0.f;
#pragma unroll
    for (int i = 0; i < 16; ++i) {
        float4 ea = eM[i];
        const int c = i * 4;
        float x0 = xb[(c + 0) * HW + pp];
        float x1 = xb[(c + 1) * HW + pp];
        float x2 = xb[(c + 2) * HW + pp];
        float x3 = xb[(c + 3) * HW + pp];
        a0 = fmaf(-x0, ea.x, a0);
        a1 = fmaf(-x1, ea.y, a1);
        a2 = fmaf(-x2, ea.z, a2);
        a3 = fmaf(-x3, ea.w, a3);
    }
    const float dMine = (a0 + a1) + (a2 + a3);
    const float dOth  = __shfl_xor(dMine, 16, 64);
    const float dA = (lane & 16) ? dOth  : dMine;
    const float dB = (lane & 16) ? dMine : dOth;
    const int myk = (dB < dA || (dB == dA && kB < kA)) ? kB : kA;

    float lsum = 0.f;
    if (lane < 16) {    // quad 0 owns the pixel's output + loss chain
        dout[IDX_OFF + b * HW + pp] = (float)myk;
        atomicAdd(&hist[myk], 1);
        const float4* qrow = (const float4*)(emb + myk * DDIM);
        float* ob = dout + OUT_OFF + b * BSTRIDE;
#pragma unroll
        for (int i = 0; i < 16; ++i) {
            float4 qv = qrow[i];
            const int c = i * 4;
            float x0 = xb[(c + 0) * HW + pp];   // L1-warm reload
            float x1 = xb[(c + 1) * HW + pp];
            float x2 = xb[(c + 2) * HW + pp];
            float x3 = xb[(c + 3) * HW + pp];
            float d0 = qv.x - x0;
            float d1 = qv.y - x1;
            float d2 = qv.z - x2;
            float d3 = qv.w - x3;
            lsum += d0 * d0 + d1 * d1 + d2 * d2 + d3 * d3;
            ob[(c + 0) * HW + pp] = x0 + d0;    // reference rounding: x + (q - x)
            ob[(c + 1) * HW + pp] = x1 + d1;
            ob[(c + 2) * HW + pp] = x2 + d2;
            ob[(c + 3) * HW + pp] = x3 + d3;
        }
    }
    for (int off = 32; off > 0; off >>= 1) lsum += __shfl_down(lsum, off, 64);
    if (lane == 0) atomicAdd(loss_acc, lsum);

    __syncthreads();
    if (t < KEMB) {
        int v = hist[t];
        if (v) atomicAdd(&counts[t], v);
    }

    // ---- Fused finalize, fence-LESS (R6/R8/R9-proven). 512 blocks now.
    __syncthreads();
    if (t == 0) lastflag = (atomicAdd(done_ctr, 1) == 511) ? 1 : 0;
    __syncthreads();
    if (lastflag) {
        if (t < KEMB) {
            int cnt = atomicAdd(&counts[t], 0);   // device-coherent read
            float pa = (float)cnt / (float)NPIX;
            float v = pa * logf(pa + 1e-10f);
#pragma unroll
            for (int off = 1; off <= 32; off <<= 1) v += __shfl_xor(v, off, 64);
            if ((t & 63) == 0) part[t >> 6] = v;
        }
        __syncthreads();
        if (t == 0) {
            float s = 0.f;
#pragma unroll
            for (int i = 0; i < 8; ++i) s += part[i];
            dout[PERP_OFF] = expf(-s);
            dout[0] = 0.25f * atomicAdd(loss_acc, 0.0f) / 8388608.0f;
        }
    }
}

extern "C" void kernel_launch(void* const* d_in, const int* in_sizes, int n_in,
                              void* d_out, int out_size, void* d_ws, size_t ws_size,
                              hipStream_t stream) {
    const float* in  = (const float*)d_in[0];   // 8388608 elems
    const float* emb = (const float*)d_in[1];   // 32768 elems
    float* dout = (float*)d_out;
    int*   counts   = (int*)d_ws;
    float* hnorms   = (float*)((char*)d_ws + 2048);
    float* loss_acc = (float*)((char*)d_ws + 4096);
    int*   done_ctr = (int*)((char*)d_ws + 4160);
    unsigned short* eh_t = (unsigned short*)((char*)d_ws + 8192);
    unsigned short* el_t = eh_t + KEMB * DDIM;   // 64 KB scaled-l table

    vq_init<<<512, 64, 0, stream>>>(emb, counts, hnorms, loss_acc, done_ctr, eh_t, el_t);
    vq_main<<<512, 1024, 0, stream>>>(in, emb, eh_t, el_t, hnorms, counts, loss_acc, done_ctr, dout);
}

// Round 12
// 154.240 us; speedup vs baseline: 1.4733x; 1.4733x over previous
//
#include <hip/hip_runtime.h>
#include <hip/hip_fp16.h>
#include <math.h>

// Problem constants
#define NPIX   131072      // B*H*W = 32*64*64
#define KEMB   512
#define DDIM   64
#define HW     4096        // H*W
#define BSTRIDE 262144     // C*H*W

// d_out flat layout (float32): [loss(1) | out(8388608) | perplexity(1) | indices(131072)]
#define OUT_OFF  1
#define PERP_OFF 8388609
#define IDX_OFF  8388610

typedef __attribute__((ext_vector_type(8))) _Float16 f16x8;    // MFMA A/B frag (4 VGPRs)
typedef __attribute__((ext_vector_type(4))) float f32x4;       // MFMA C/D frag

// SESSION LEDGER (proven on this problem):
//  - R9 = 82us vq_main (total 153.5, best): f16 2-split K-loop, both tables
//    LDS (132KB), 1-tile LDS prefetch pipeline, med3/min top-2, build-after-
//    barrier, 256x1024 @(1024,4), 16 waves/CU, fence-LESS ticket finalize.
//  - R11 3rd spill confirmation: <=64-reg config UNREACHABLE for this kernel
//    (even halved live set spills: VGPR=32, +55MB scratch). Occupancy door is
//    CLOSED: LDS tables -> 1 block/CU; >64 regs -> 16 waves/CU. Structure
//    is fixed; wins must come from ILP / shorter dep chains.
//  - R10: setprio around near-lockstep MFMA cluster regressed (-4us). Dropped.
//  - __threadfence() = ~2x curse (L2 WB/INV storm). NEVER.
//  - R12 (this): single change vs R9 — unroll K-loop x2, split top-2 state by
//    tile parity (4 independent select chains instead of 2; 2-iteration dep
//    gap), merge parities at the end with the value-then-index comparator.
//    Selection-equivalent; distance/rescore/output/loss chains bitwise == R9.
//
// 2-split f16 scheme (absmax 0 in R2..R11): x = h + l/2048 + r, |r|<=2^-21|x|.
// l pre-scaled by 2^11 (exact pow2) stays in f16 normal range. Products kept:
// hh + (h*l'+l'*h)/2048; dropped terms ~1e-4 absolute, and the exact fp32
// top-2 rescore decides the final index.

// ws layout: [0,2048) int counts | [2048,4096) float hnorms | [4096] loss |
//            [4160] done_ctr | [8192,73728) eh_t (f16 high, frag-linear, 64KB) |
//            [73728,139264) el_t (f16 low pre-scaled by 2^11, frag-linear, 64KB)
// frag-linear: idx = ct*1024 + ks*512 + (quad*16+col)*8 + j  (R5-proven).
__global__ void vq_init(const float* __restrict__ emb, int* __restrict__ counts,
                        float* __restrict__ hnorms, float* __restrict__ loss_acc,
                        int* __restrict__ done_ctr,
                        unsigned short* __restrict__ eh_t,
                        unsigned short* __restrict__ el_t) {
    const int k = blockIdx.x;             // code
    const int c = threadIdx.x;            // channel
    const int ct = k >> 4, cl = k & 15;
    const int ks = c >> 5, qd = (c >> 3) & 3, j = c & 7;
    float x = emb[k * DDIM + c];
    _Float16 h = (_Float16)x;             // v_cvt_f16_f32, RTNE
    float r1 = x - (float)h;              // exact (Sterbenz)
    _Float16 l = (_Float16)(r1 * 2048.0f);
    const int dst = ct * 1024 + ks * 512 + (qd * 16 + cl) * 8 + j;
    ((_Float16*)eh_t)[dst] = h;
    ((_Float16*)el_t)[dst] = l;
    float s = x * x;
#pragma unroll
    for (int off = 1; off <= 32; off <<= 1) s += __shfl_xor(s, off, 64);
    if (c == 0) {
        hnorms[k] = 0.5f * s;
        counts[k] = 0;
        if (k == 0) { *loss_acc = 0.f; *done_ctr = 0; }
    }
}

// One MFMA+select step for a tile, writing into the chain selected by PAR
// (literal 0/1 -> static indexing, rule-#20 safe). Arithmetic bitwise == R9.
#define SELECT_UPDATE(PAR, TT, AH, AL, CT)                                   \
    {                                                                        \
        const f32x4 hn = *(const f32x4*)&hn_lds[(CT) * 16 + quad * 4];       \
        _Pragma("unroll")                                                    \
        for (int r = 0; r < 4; ++r) {                                        \
            const int kk = (CT) * 16 + quad * 4 + r;                         \
            const float sc = hn[r] - ((AH)[r] + (AL)[r] * 4.8828125e-4f);    \
            const bool c1 = sc < v1[PAR][TT];                                \
            const bool c2 = sc < v2[PAR][TT];                                \
            const int nk2 = c1 ? k1[PAR][TT] : (c2 ? kk : k2[PAR][TT]);      \
            const int nk1 = c1 ? kk : k1[PAR][TT];                           \
            v2[PAR][TT] = __builtin_amdgcn_fmed3f(v1[PAR][TT], v2[PAR][TT], sc); \
            v1[PAR][TT] = fminf(v1[PAR][TT], sc);                            \
            k1[PAR][TT] = nk1; k2[PAR][TT] = nk2;                            \
        }                                                                    \
    }

// 256 blocks x 1024 threads, 1 block/CU, 16 waves (proven shape). LDS 132KB:
// both f16 tables resident -> K-loop pure LDS + 12 MFMA/tile, barrier-free,
// unrolled x2 with parity-split top-2 chains (4 independent chains).
__global__ __launch_bounds__(1024, 4) void vq_main(
    const float* __restrict__ in, const float* __restrict__ emb,
    const unsigned short* __restrict__ eh_t, const unsigned short* __restrict__ el_t,
    const float* __restrict__ hnorms, int* __restrict__ counts,
    float* __restrict__ loss_acc, int* __restrict__ done_ctr,
    float* __restrict__ dout)
{
    __shared__ __align__(16) _Float16 eh_l[KEMB * DDIM];   // 64 KB
    __shared__ __align__(16) _Float16 el_l[KEMB * DDIM];   // 64 KB
    __shared__ __align__(16) float hn_lds[KEMB];           // 2 KB
    __shared__ int hist[KEMB];                             // 2 KB
    __shared__ float part[8];
    __shared__ int lastflag;

    const int t    = threadIdx.x;         // 0..1023
    const int lane = t & 63;
    const int wv   = t >> 6;              // wave id 0..15
    const int quad = lane >> 4;
    const int col  = lane & 15;
    const int b    = blockIdx.x >> 3;                        // 8 blocks per image
    const int p0   = ((blockIdx.x & 7) << 9) | (wv << 5);    // first of this wave's 32 px
    const float* xb = in + b * BSTRIDE;

    if (t < KEMB) hist[t] = 0;
    if (t < 128) ((float4*)hn_lds)[t] = ((const float4*)hnorms)[t];

    // ---- Stage both tables into LDS: linear 16B/lane copies (proven).
#pragma unroll
    for (int i = 0; i < 4; ++i) {
        const int f = (t + i * 1024) * 8;
        *(f16x8*)&eh_l[f] = *(const f16x8*)((const _Float16*)eh_t + f);
        *(f16x8*)&el_l[f] = *(const f16x8*)((const _Float16*)el_t + f);
    }

    __syncthreads();   // tables + hn + hist ready

    // ---- Build x B-fragments AFTER the barrier (R9-proven): registers only.
    f16x8 xh[2][2], xl[2][2];
#pragma unroll
    for (int tt = 0; tt < 2; ++tt) {
#pragma unroll
        for (int s = 0; s < 2; ++s) {
            const int ppb = p0 + tt * 16 + col;
            const int c0  = s * 32 + quad * 8;
            f16x8 vh, vl;
#pragma unroll
            for (int j = 0; j < 8; ++j) {
                float x = xb[(c0 + j) * HW + ppb];
                _Float16 h = (_Float16)x;
                float r1 = x - (float)h;
                vh[j] = h;
                vl[j] = (_Float16)(r1 * 2048.0f);
            }
            xh[tt][s] = vh; xl[tt][s] = vl;
        }
    }

    // ---- K-loop over 32 code tiles, unrolled x2 with parity-split chains.
    float v1[2][2], v2[2][2]; int k1[2][2], k2[2][2];   // [parity][tt], static idx
#pragma unroll
    for (int p = 0; p < 2; ++p)
#pragma unroll
        for (int tt = 0; tt < 2; ++tt) {
            v1[p][tt] = 3.402823466e38f; v2[p][tt] = 3.402823466e38f;
            k1[p][tt] = 0; k2[p][tt] = 0;
        }

    // Prologue: tile 0 fragments
    f16x8 Ah0 = *(const f16x8*)&eh_l[lane * 8];
    f16x8 Ah1 = *(const f16x8*)&eh_l[lane * 8 + 512];
    f16x8 Al0 = *(const f16x8*)&el_l[lane * 8];
    f16x8 Al1 = *(const f16x8*)&el_l[lane * 8 + 512];

    for (int ct = 0; ct < 32; ct += 2) {
        // ---------- even tile (ct) ----------
        f32x4 a0h = (f32x4){0.f, 0.f, 0.f, 0.f};
        f32x4 a0l = (f32x4){0.f, 0.f, 0.f, 0.f};
        f32x4 a1h = (f32x4){0.f, 0.f, 0.f, 0.f};
        f32x4 a1l = (f32x4){0.f, 0.f, 0.f, 0.f};
        a0h = __builtin_amdgcn_mfma_f32_16x16x32_f16(Ah0, xh[0][0], a0h, 0, 0, 0);
        a0l = __builtin_amdgcn_mfma_f32_16x16x32_f16(Ah0, xl[0][0], a0l, 0, 0, 0);
        a0l = __builtin_amdgcn_mfma_f32_16x16x32_f16(Al0, xh[0][0], a0l, 0, 0, 0);
        a1h = __builtin_amdgcn_mfma_f32_16x16x32_f16(Ah0, xh[1][0], a1h, 0, 0, 0);
        a1l = __builtin_amdgcn_mfma_f32_16x16x32_f16(Ah0, xl[1][0], a1l, 0, 0, 0);
        a1l = __builtin_amdgcn_mfma_f32_16x16x32_f16(Al0, xh[1][0], a1l, 0, 0, 0);
        a0h = __builtin_amdgcn_mfma_f32_16x16x32_f16(Ah1, xh[0][1], a0h, 0, 0, 0);
        a0l = __builtin_amdgcn_mfma_f32_16x16x32_f16(Ah1, xl[0][1], a0l, 0, 0, 0);
        a0l = __builtin_amdgcn_mfma_f32_16x16x32_f16(Al1, xh[0][1], a0l, 0, 0, 0);
        a1h = __builtin_amdgcn_mfma_f32_16x16x32_f16(Ah1, xh[1][1], a1h, 0, 0, 0);
        a1l = __builtin_amdgcn_mfma_f32_16x16x32_f16(Ah1, xl[1][1], a1l, 0, 0, 0);
        a1l = __builtin_amdgcn_mfma_f32_16x16x32_f16(Al1, xh[1][1], a1l, 0, 0, 0);

        // Prefetch odd tile (ct+1) fragments; drain under the even selects.
        {
            const int nbase = (ct + 1) * 1024 + lane * 8;
            Ah0 = *(const f16x8*)&eh_l[nbase];
            Ah1 = *(const f16x8*)&eh_l[nbase + 512];
            Al0 = *(const f16x8*)&el_l[nbase];
            Al1 = *(const f16x8*)&el_l[nbase + 512];
        }

        SELECT_UPDATE(0, 0, a0h, a0l, ct)
        SELECT_UPDATE(0, 1, a1h, a1l, ct)

        // ---------- odd tile (ct+1) ----------
        f32x4 b0h = (f32x4){0.f, 0.f, 0.f, 0.f};
        f32x4 b0l = (f32x4){0.f, 0.f, 0.f, 0.f};
        f32x4 b1h = (f32x4){0.f, 0.f, 0.f, 0.f};
        f32x4 b1l = (f32x4){0.f, 0.f, 0.f, 0.f};
        b0h = __builtin_amdgcn_mfma_f32_16x16x32_f16(Ah0, xh[0][0], b0h, 0, 0, 0);
        b0l = __builtin_amdgcn_mfma_f32_16x16x32_f16(Ah0, xl[0][0], b0l, 0, 0, 0);
        b0l = __builtin_amdgcn_mfma_f32_16x16x32_f16(Al0, xh[0][0], b0l, 0, 0, 0);
        b1h = __builtin_amdgcn_mfma_f32_16x16x32_f16(Ah0, xh[1][0], b1h, 0, 0, 0);
        b1l = __builtin_amdgcn_mfma_f32_16x16x32_f16(Ah0, xl[1][0], b1l, 0, 0, 0);
        b1l = __builtin_amdgcn_mfma_f32_16x16x32_f16(Al0, xh[1][0], b1l, 0, 0, 0);
        b0h = __builtin_amdgcn_mfma_f32_16x16x32_f16(Ah1, xh[0][1], b0h, 0, 0, 0);
        b0l = __builtin_amdgcn_mfma_f32_16x16x32_f16(Ah1, xl[0][1], b0l, 0, 0, 0);
        b0l = __builtin_amdgcn_mfma_f32_16x16x32_f16(Al1, xh[0][1], b0l, 0, 0, 0);
        b1h = __builtin_amdgcn_mfma_f32_16x16x32_f16(Ah1, xh[1][1], b1h, 0, 0, 0);
        b1l = __builtin_amdgcn_mfma_f32_16x16x32_f16(Ah1, xl[1][1], b1l, 0, 0, 0);
        b1l = __builtin_amdgcn_mfma_f32_16x16x32_f16(Al1, xh[1][1], b1l, 0, 0, 0);

        // Prefetch next even tile ((ct+2)&31 wraps harmlessly at the end).
        {
            const int nbase = ((ct + 2) & 31) * 1024 + lane * 8;
            Ah0 = *(const f16x8*)&eh_l[nbase];
            Ah1 = *(const f16x8*)&eh_l[nbase + 512];
            Al0 = *(const f16x8*)&el_l[nbase];
            Al1 = *(const f16x8*)&el_l[nbase + 512];
        }

        SELECT_UPDATE(1, 0, b0h, b0l, ct + 1)
        SELECT_UPDATE(1, 1, b1h, b1l, ct + 1)
    }

    // ---- Merge parity chains (value-then-index comparator — exact global
    // tie-break: within each chain kk increasing, ties kept incumbent).
    float V1[2], V2[2]; int K1[2], K2[2];
#pragma unroll
    for (int tt = 0; tt < 2; ++tt) {
        bool aF = (v1[0][tt] < v1[1][tt]) || (v1[0][tt] == v1[1][tt] && k1[0][tt] < k1[1][tt]);
        float t1 = aF ? v1[0][tt] : v1[1][tt];  int u1 = aF ? k1[0][tt] : k1[1][tt];
        float tl = aF ? v1[1][tt] : v1[0][tt];  int ul = aF ? k1[1][tt] : k1[0][tt];
        bool bS = (v2[0][tt] < v2[1][tt]) || (v2[0][tt] == v2[1][tt] && k2[0][tt] < k2[1][tt]);
        float tc = bS ? v2[0][tt] : v2[1][tt];  int uc = bS ? k2[0][tt] : k2[1][tt];
        bool lS = (tl < tc) || (tl == tc && ul < uc);
        V1[tt] = t1; K1[tt] = u1;
        V2[tt] = lS ? tl : tc; K2[tt] = lS ? ul : uc;
    }

    // Cross-quad top-2 merge (lanes l, l^16, l^32 share pixel-col) — R0 verbatim
#pragma unroll
    for (int tt = 0; tt < 2; ++tt) {
#pragma unroll
        for (int off = 16; off <= 32; off <<= 1) {
            float w1 = __shfl_xor(V1[tt], off, 64); int j1 = __shfl_xor(K1[tt], off, 64);
            float w2 = __shfl_xor(V2[tt], off, 64); int j2 = __shfl_xor(K2[tt], off, 64);
            bool aF = (V1[tt] < w1) || (V1[tt] == w1 && K1[tt] < j1);
            float t1 = aF ? V1[tt] : w1;  int u1 = aF ? K1[tt] : j1;
            float tl = aF ? w1 : V1[tt];  int ul = aF ? j1 : K1[tt];      // loser of firsts
            bool bS = (V2[tt] < w2) || (V2[tt] == w2 && K2[tt] < j2);
            float tc = bS ? V2[tt] : w2;  int uc = bS ? K2[tt] : j2;      // better of seconds
            bool lS = (tl < tc) || (tl == tc && ul < uc);
            V1[tt] = t1; K1[tt] = u1;
            V2[tt] = lS ? tl : tc; K2[tt] = lS ? ul : uc;
        }
    }

    // Pixel q = lane&31; lanes l and l+32 handle the same pixel (tt = (l>>4)&1).
    const int q    = lane & 31;
    const int pp   = p0 + q;
    const int tsel = (lane >> 4) & 1;
    const int kA = tsel ? K1[1] : K1[0];
    const int kB = tsel ? K2[1] : K2[0];

    // Exact fp32 rescore, split: lanes<32 score kA, lanes>=32 score kB.
    // Streaming x loads — ops and order bitwise == the passing kernels.
    const int kMine = (lane < 32) ? kA : kB;
    const float4* eM = (const float4*)(emb + kMine * DDIM);
    float a0 = hn_lds[kMine], a1 = 0.f, a2 = 0.f, a3 = 0.f;
#pragma unroll
    for (int i = 0; i < 16; ++i) {
        float4 ea = eM[i];
        const int c = i * 4;
        float x0 = xb[(c + 0) * HW + pp];
        float x1 = xb[(c + 1) * HW + pp];
        float x2 = xb[(c + 2) * HW + pp];
        float x3 = xb[(c + 3) * HW + pp];
        a0 = fmaf(-x0, ea.x, a0);
        a1 = fmaf(-x1, ea.y, a1);
        a2 = fmaf(-x2, ea.z, a2);
        a3 = fmaf(-x3, ea.w, a3);
    }
    const float dMine = (a0 + a1) + (a2 + a3);
    const float dOth  = __shfl_xor(dMine, 32, 64);
    const float dA = (lane < 32) ? dMine : dOth;
    const float dB = (lane < 32) ? dOth  : dMine;
    const int myk = (dB < dA || (dB == dA && kB < kA)) ? kB : kA;

    float lsum = 0.f;
    if (lane < 32) {
        dout[IDX_OFF + b * HW + pp] = (float)myk;
        atomicAdd(&hist[myk], 1);
        const float4* qrow = (const float4*)(emb + myk * DDIM);
        float* ob = dout + OUT_OFF + b * BSTRIDE;
#pragma unroll
        for (int i = 0; i < 16; ++i) {
            float4 qv = qrow[i];
            const int c = i * 4;
            float x0 = xb[(c + 0) * HW + pp];   // L1-warm reload (just read above)
            float x1 = xb[(c + 1) * HW + pp];
            float x2 = xb[(c + 2) * HW + pp];
            float x3 = xb[(c + 3) * HW + pp];
            float d0 = qv.x - x0;
            float d1 = qv.y - x1;
            float d2 = qv.z - x2;
            float d3 = qv.w - x3;
            lsum += d0 * d0 + d1 * d1 + d2 * d2 + d3 * d3;
            ob[(c + 0) * HW + pp] = x0 + d0;    // reference rounding: x + (q - x)
            ob[(c + 1) * HW + pp] = x1 + d1;
            ob[(c + 2) * HW + pp] = x2 + d2;
            ob[(c + 3) * HW + pp] = x3 + d3;
        }
    }
    for (int off = 32; off > 0; off >>= 1) lsum += __shfl_down(lsum, off, 64);
    if (lane == 0) atomicAdd(loss_acc, lsum);

    __syncthreads();
    if (t < KEMB) {
        int v = hist[t];
        if (v) atomicAdd(&counts[t], v);
    }

    // ---- Fused finalize, fence-LESS (R6/R8/R9-proven).
    __syncthreads();
    if (t == 0) lastflag = (atomicAdd(done_ctr, 1) == 255) ? 1 : 0;
    __syncthreads();
    if (lastflag) {
        if (t < KEMB) {
            int cnt = atomicAdd(&counts[t], 0);   // device-coherent read
            float pa = (float)cnt / (float)NPIX;
            float v = pa * logf(pa + 1e-10f);
#pragma unroll
            for (int off = 1; off <= 32; off <<= 1) v += __shfl_xor(v, off, 64);
            if ((t & 63) == 0) part[t >> 6] = v;
        }
        __syncthreads();
        if (t == 0) {
            float s = 0.f;
#pragma unroll
            for (int i = 0; i < 8; ++i) s += part[i];
            dout[PERP_OFF] = expf(-s);
            dout[0] = 0.25f * atomicAdd(loss_acc, 0.0f) / 8388608.0f;
        }
    }
}

extern "C" void kernel_launch(void* const* d_in, const int* in_sizes, int n_in,
                              void* d_out, int out_size, void* d_ws, size_t ws_size,
                              hipStream_t stream) {
    const float* in  = (const float*)d_in[0];   // 8388608 elems
    const float* emb = (const float*)d_in[1];   // 32768 elems
    float* dout = (float*)d_out;
    int*   counts   = (int*)d_ws;
    float* hnorms   = (float*)((char*)d_ws + 2048);
    float* loss_acc = (float*)((char*)d_ws + 4096);
    int*   done_ctr = (int*)((char*)d_ws + 4160);
    unsigned short* eh_t = (unsigned short*)((char*)d_ws + 8192);
    unsigned short* el_t = eh_t + KEMB * DDIM;   // 64 KB scaled-l table

    vq_init<<<512, 64, 0, stream>>>(emb, counts, hnorms, loss_acc, done_ctr, eh_t, el_t);
    vq_main<<<256, 1024, 0, stream>>>(in, emb, eh_t, el_t, hnorms, counts, loss_acc, done_ctr, dout);
}